// Round 3
// baseline (353.576 us; speedup 1.0000x reference)
//
#include <hip/hip_runtime.h>

// LearnableTensorSquare: out[z,k] = sum_ij (W@T)[k,i*128+j] * f[z,i] * f[z,j]
// f = [ones, features], Z=16384, N=128, K=128, DIM_TS=2080. All-f16 pipeline.
// k_wf : W -> frag-ready f16 layout (in ws, after K3).
// k_wt : K3 partials = W@T. Wave-independent, no LDS/barriers, explicit 2-stage
//        register prefetch pipeline, 2x d-split, 8 blocks/CU -> HBM-saturating.
//        Partials written to d_out scratch (8 MB), summed by k_sum into ws.
// k_qf : out = sum_i A_i @ K3_i^T. 32x32x16 f16 MFMA; A gen'd in registers;
//        B staged to XOR-swizzled LDS via global_load_lds w/ pre-swizzled source.

#define ZTOT 16384
#define NIN  127
#define KOUT 128
#define DTS  2080
#define PTOT 16384  // N*N

typedef _Float16 h8 __attribute__((ext_vector_type(8)));
typedef _Float16 h2 __attribute__((ext_vector_type(2)));
typedef float f32x4 __attribute__((ext_vector_type(4)));
typedef float f32x16 __attribute__((ext_vector_type(16)));

static __device__ __forceinline__ void gl16(const void* g, void* l) {
  __builtin_amdgcn_global_load_lds((const __attribute__((address_space(1))) unsigned int*)g,
                                   (__attribute__((address_space(3))) unsigned int*)l, 16, 0, 0);
}

// ---- k_wf: Wf[unit=s*8+kg][lane][e] = f16(W[kg*16+(lane&15)][s*32+(lane>>4)*8+e])
__global__ __launch_bounds__(256) void k_wf(const float* __restrict__ W,
                                            _Float16* __restrict__ Wf) {
  const int t = threadIdx.x, lane = t & 63;
  const int unit = blockIdx.x * 4 + (t >> 6);
  if (unit >= 520) return;
  const int s = unit >> 3, kg = unit & 7;
  const int krow = kg * 16 + (lane & 15);
  const int dbase = s * 32 + ((lane >> 4) << 3);
  h8 v;
#pragma unroll
  for (int e = 0; e < 8; ++e) v[e] = (_Float16)W[(size_t)krow * DTS + dbase + e];
  *(h8*)(Wf + ((size_t)unit * 64 + lane) * 8) = v;
}

// ---- k_wt: K3p[dh][k][p] = sum_{d in half dh} W[k][d]*T[d][p], f16.
// grid 2048 = 1024 p-tiles x 2 d-halves. Wave w: k-rows [w*32, w*32+32).
// No barriers, no LDS; explicit 2-stage prefetch pipeline.
__global__ __launch_bounds__(256, 6) void k_wt(const float* __restrict__ T,
                                               const _Float16* __restrict__ Wf,
                                               _Float16* __restrict__ K3p) {
  const int t = threadIdx.x, lane = t & 63, w = t >> 6;
  const int ptile = blockIdx.x >> 1, dh = blockIdx.x & 1;
  const int p0 = ptile * 16;
  const int prow = p0 + (lane & 15);
  const int dg = (lane >> 4) << 3;  // 0,8,16,24
  _Float16* K3 = K3p + (size_t)dh * (128 * PTOT);
  const _Float16* wf0 = Wf + (size_t)w * 1024 + (size_t)lane * 8;

  f32x4 acc0 = {}, acc1 = {};
  float fc[8];
  h8 ac0, ac1;
  // prologue: load chunk s = dh
  {
    const size_t tb = (size_t)(dh * 32 + dg) * PTOT + prow;
#pragma unroll
    for (int e = 0; e < 8; ++e) fc[e] = T[tb + (size_t)e * PTOT];
    ac0 = *(const h8*)(wf0 + (size_t)dh * 4096);
    ac1 = *(const h8*)(wf0 + (size_t)dh * 4096 + 512);
  }
  int s = dh;
  for (; s + 2 < 65; s += 2) {
    // issue next chunk's loads (address-independent of current MFMA)
    float fn[8];
    h8 an0, an1;
    const int sn = s + 2;
    const size_t tb = (size_t)(sn * 32 + dg) * PTOT + prow;
#pragma unroll
    for (int e = 0; e < 8; ++e) fn[e] = T[tb + (size_t)e * PTOT];
    an0 = *(const h8*)(wf0 + (size_t)sn * 4096);
    an1 = *(const h8*)(wf0 + (size_t)sn * 4096 + 512);
    // compute current chunk
    h8 b;
#pragma unroll
    for (int e = 0; e < 8; ++e) b[e] = (_Float16)fc[e];
    acc0 = __builtin_amdgcn_mfma_f32_16x16x32_f16(ac0, b, acc0, 0, 0, 0);
    acc1 = __builtin_amdgcn_mfma_f32_16x16x32_f16(ac1, b, acc1, 0, 0, 0);
#pragma unroll
    for (int e = 0; e < 8; ++e) fc[e] = fn[e];
    ac0 = an0; ac1 = an1;
  }
  {  // epilogue chunk
    h8 b;
#pragma unroll
    for (int e = 0; e < 8; ++e) b[e] = (_Float16)fc[e];
    acc0 = __builtin_amdgcn_mfma_f32_16x16x32_f16(ac0, b, acc0, 0, 0, 0);
    acc1 = __builtin_amdgcn_mfma_f32_16x16x32_f16(ac1, b, acc1, 0, 0, 0);
  }
  const int rbase = (lane >> 4) << 2;
#pragma unroll
  for (int r = 0; r < 4; ++r) {
    K3[(size_t)(w * 32 + rbase + r) * PTOT + prow] = (_Float16)acc0[r];
    K3[(size_t)(w * 32 + 16 + rbase + r) * PTOT + prow] = (_Float16)acc1[r];
  }
}

// ---- k_sum: K3h = K3a + K3b (f16, 2M elems)
__global__ __launch_bounds__(256) void k_sum(const _Float16* __restrict__ A,
                                             const _Float16* __restrict__ B,
                                             _Float16* __restrict__ O) {
  const size_t i = ((size_t)blockIdx.x * 256 + threadIdx.x) * 8;
  const h8 a = *(const h8*)(A + i);
  const h8 b = *(const h8*)(B + i);
  *(h8*)(O + i) = a + b;
}

// ---- k_qf: grid 512 = 128 z-tiles x 4 i-classes; block 256 = 4 waves (2 zg x 2 kg).
// Wave tile 64z x 64k (m=2, n=2, kc=8). B tile [128k][128j] f16 dbuf in LDS.
__global__ __launch_bounds__(256, 2) void k_qf(const float* __restrict__ features,
                                               const _Float16* __restrict__ K3,
                                               float* __restrict__ out) {
  __shared__ __align__(16) _Float16 B0[16384];
  __shared__ __align__(16) _Float16 B1[16384];
  __shared__ _Float16 fT[32 * 136];
  const int t = threadIdx.x, lane = t & 63, w = t >> 6;
  const int zg = w >> 1, kg = w & 1, hg = lane >> 5, l31 = lane & 31;
  const int zb = blockIdx.x >> 2, ic = blockIdx.x & 3;
  const int z0 = zb * 128, i0 = ic * 32;

  // f-tile [z 0..127][j 0..127] f16, XOR-swizzled, into B0 (transient)
  {
    const int row = t >> 1, hf = t & 1;
    const float* fr = features + (size_t)(z0 + row) * NIN;
    const int rs = (row & 7) << 4;
#pragma unroll
    for (int qb = 0; qb < 8; ++qb) {
      h8 v;
#pragma unroll
      for (int e = 0; e < 8; ++e) {
        const int j = hf * 64 + qb * 8 + e;
        v[e] = (j == 0) ? (_Float16)1.0f : (_Float16)fr[j - 1];
      }
      *(h8*)((char*)B0 + row * 256 + (((hf * 8 + qb) * 16) ^ rs)) = v;
    }
  }
  // fT[i 0..31][z 0..127] (fi lookup table, transposed for conflict-free reads)
  {
    const int z = t >> 1, ih = t & 1;
#pragma unroll
    for (int q = 0; q < 16; ++q) {
      const int il = ih * 16 + q, gi = i0 + il;
      const float fv = (gi == 0) ? 1.0f : features[(size_t)(z0 + z) * NIN + gi - 1];
      fT[il * 136 + z] = (_Float16)fv;
    }
  }
  __syncthreads();

  // fj regs: per lane, rows (zg*64 + m*32 + l31), j = kc*16 + hg*8 + e
  h8 fj8[2][8];
#pragma unroll
  for (int m = 0; m < 2; ++m) {
    const int rowm = zg * 64 + m * 32 + l31;
    const int rs = (rowm & 7) << 4;
#pragma unroll
    for (int kc = 0; kc < 8; ++kc)
      fj8[m][kc] = *(const h8*)((const char*)B0 + rowm * 256 + (((kc * 2 + hg) * 16) ^ rs));
  }
  __syncthreads();

  // B staging: linear LDS dest, inverse-swizzled global source (rule #21)
  const _Float16* Kbase = K3 + (size_t)i0 * 128;
#define STAGE_B(BUF, IPH)                                                      \
  {                                                                            \
    const _Float16* src = Kbase + (IPH) * 128;                                 \
    _Pragma("unroll") for (int r = 0; r < 8; ++r) {                            \
      const int Lb = r * 4096 + w * 1024;                                      \
      const int row = (Lb >> 8) + (lane >> 4);                                 \
      const int us = (lane & 15) ^ (row & 7);                                  \
      gl16(src + (size_t)row * PTOT + us * 8, (char*)(BUF) + Lb);              \
    }                                                                          \
  }

  f32x16 acc[2][2] = {};
  STAGE_B(B0, 0)
  __syncthreads();

  const int rs0 = (l31 & 7) << 4;  // swizzle term: rows kg*64(+32)+l31 -> l31&7
  const int brow0 = (kg * 64 + l31) * 256;
  const int brow1 = (kg * 64 + 32 + l31) * 256;

#define PHASE(CURB, NXTB, PH, DO_STAGE)                                        \
  {                                                                            \
    if (DO_STAGE) STAGE_B(NXTB, (PH) + 1)                                      \
    const _Float16 f0 = fT[(PH) * 136 + zg * 64 + l31];                        \
    const _Float16 f1 = fT[(PH) * 136 + zg * 64 + 32 + l31];                   \
    const h2 fi0 = {f0, f0};                                                   \
    const h2 fi1 = {f1, f1};                                                   \
    _Pragma("unroll") for (int kc = 0; kc < 8; ++kc) {                         \
      const int uoff = ((kc * 2 + hg) * 16) ^ rs0;                             \
      const h8 b0 = *(const h8*)((const char*)(CURB) + brow0 + uoff);          \
      const h8 b1 = *(const h8*)((const char*)(CURB) + brow1 + uoff);          \
      h8 a0, a1;                                                               \
      _Pragma("unroll") for (int r = 0; r < 4; ++r) {                          \
        const h2 j0 = {fj8[0][kc][2 * r], fj8[0][kc][2 * r + 1]};              \
        const h2 j1 = {fj8[1][kc][2 * r], fj8[1][kc][2 * r + 1]};              \
        const h2 p0 = fi0 * j0;                                                \
        const h2 p1 = fi1 * j1;                                                \
        a0[2 * r] = p0[0]; a0[2 * r + 1] = p0[1];                              \
        a1[2 * r] = p1[0]; a1[2 * r + 1] = p1[1];                              \
      }                                                                        \
      acc[0][0] = __builtin_amdgcn_mfma_f32_32x32x16_f16(a0, b0, acc[0][0], 0, 0, 0); \
      acc[0][1] = __builtin_amdgcn_mfma_f32_32x32x16_f16(a0, b1, acc[0][1], 0, 0, 0); \
      acc[1][0] = __builtin_amdgcn_mfma_f32_32x32x16_f16(a1, b0, acc[1][0], 0, 0, 0); \
      acc[1][1] = __builtin_amdgcn_mfma_f32_32x32x16_f16(a1, b1, acc[1][1], 0, 0, 0); \
    }                                                                          \
    __syncthreads();                                                           \
  }

  for (int pb = 0; pb < 16; ++pb) {
    PHASE(B0, B1, pb * 2, true)
    PHASE(B1, B0, pb * 2 + 1, (pb < 15))
  }

  // C/D 32x32: col = l31, row = (r&3) + 8*(r>>2) + 4*hg
  const int kq = kg * 64 + l31;
#pragma unroll
  for (int m = 0; m < 2; ++m)
#pragma unroll
    for (int n = 0; n < 2; ++n)
#pragma unroll
      for (int r = 0; r < 16; ++r) {
        const int zr = (r & 3) + ((r >> 2) << 3) + (hg << 2);
        const int z = z0 + zg * 64 + m * 32 + zr;
        atomicAdd(out + (size_t)z * KOUT + kq + n * 32, acc[m][n][r]);
      }
}

extern "C" void kernel_launch(void* const* d_in, const int* in_sizes, int n_in,
                              void* d_out, int out_size, void* d_ws, size_t ws_size,
                              hipStream_t stream) {
  const float* features = (const float*)d_in[0];  // [16384, 127]
  const float* W        = (const float*)d_in[1];  // [128, 2080]
  const float* T        = (const float*)d_in[2];  // [2080, 16384]
  float* out = (float*)d_out;                     // [16384, 128] f32

  _Float16* K3h = (_Float16*)d_ws;                // [128, 16384] f16 (4 MB)
  _Float16* Wf  = K3h + (size_t)2 * 1024 * 1024;  // 532 KB, ws total ~4.6 MB
  _Float16* K3a = (_Float16*)d_out;               // partials in d_out scratch (8 MB)
  _Float16* K3b = K3a + (size_t)2 * 1024 * 1024;

  k_wf<<<dim3(130), dim3(256), 0, stream>>>(W, Wf);
  k_wt<<<dim3(2048), dim3(256), 0, stream>>>(T, Wf, K3a);
  k_sum<<<dim3(1024), dim3(256), 0, stream>>>(K3a, K3b, K3h);
  hipMemsetAsync(d_out, 0, (size_t)ZTOT * KOUT * sizeof(float), stream);
  k_qf<<<dim3(512), dim3(256), 0, stream>>>(features, K3h, out);
}

// Round 5
// 289.619 us; speedup vs baseline: 1.2208x; 1.2208x over previous
//
#include <hip/hip_runtime.h>

// LearnableTensorSquare: out[z,k] = sum_ij (W@T)[k,i*128+j] * f[z,i] * f[z,j]
// f = [ones, features], Z=16384, N=128, K=128, DIM_TS=2080. All-f16 pipeline.
// k_wf : W -> frag-ready f16 layout (in ws, after K3).
// k_wt : K3 partials = W@T. v3: contiguous float4 T reads + LDS transpose
//        ([p][d] f16 tile, XOR-swizzled: b128 frag reads conflict-free),
//        dbuf + reg prefetch, 512 blocks (2/CU). Partials -> d_out scratch.
// k_sum: sum the two d-chunk partials into ws.
// k_qf : out = sum_i A_i @ K3_i^T. 32x32x16 f16 MFMA; A gen'd in registers;
//        B staged to XOR-swizzled LDS via global_load_lds w/ pre-swizzled source.

#define ZTOT 16384
#define NIN  127
#define KOUT 128
#define DTS  2080
#define PTOT 16384  // N*N

typedef _Float16 h8 __attribute__((ext_vector_type(8)));
typedef _Float16 h2 __attribute__((ext_vector_type(2)));
typedef float f32x4 __attribute__((ext_vector_type(4)));
typedef float f32x16 __attribute__((ext_vector_type(16)));

static __device__ __forceinline__ void gl16(const void* g, void* l) {
  __builtin_amdgcn_global_load_lds((const __attribute__((address_space(1))) unsigned int*)g,
                                   (__attribute__((address_space(3))) unsigned int*)l, 16, 0, 0);
}

static __device__ __forceinline__ unsigned int pk16(float a, float b) {
  return __builtin_bit_cast(unsigned int, __builtin_amdgcn_cvt_pkrtz(a, b));
}

// ---- k_wf: Wf[unit=s*8+kg][lane][e] = f16(W[kg*16+(lane&15)][s*32+(lane>>4)*8+e])
__global__ __launch_bounds__(256) void k_wf(const float* __restrict__ W,
                                            _Float16* __restrict__ Wf) {
  const int t = threadIdx.x, lane = t & 63;
  const int unit = blockIdx.x * 4 + (t >> 6);
  if (unit >= 520) return;
  const int s = unit >> 3, kg = unit & 7;
  const int krow = kg * 16 + (lane & 15);
  const int dbase = s * 32 + ((lane >> 4) << 3);
  h8 v;
#pragma unroll
  for (int e = 0; e < 8; ++e) v[e] = (_Float16)W[(size_t)krow * DTS + dbase + e];
  *(h8*)(Wf + ((size_t)unit * 64 + lane) * 8) = v;
}

// ---- k_wt v3: K3part[chunk][k][p] = sum_{d in chunk} W[k][d]*T[d][p], f16.
// grid 512 = 256 p-tiles(64) x 2 d-chunks (33/32 steps of 32 d). Block 256 = 4 waves.
// Per step: contiguous float4 loads of T row-pairs -> pkrtz -> ds_write_b32 into
// Tb[p][d] f16 (64B rows, 16B-unit swizzle u^=(p>>2)&3) -> b128 B-frags + Wf A-frags.
__global__ __launch_bounds__(256, 2) void k_wt(const float* __restrict__ T,
                                               const _Float16* __restrict__ Wf,
                                               _Float16* __restrict__ K3a,
                                               _Float16* __restrict__ K3b) {
  __shared__ __align__(16) _Float16 Tb0[64 * 32];
  __shared__ __align__(16) _Float16 Tb1[64 * 32];
  const int t = threadIdx.x, lane = t & 63, w = t >> 6;
  const int ptile = (int)blockIdx.x >> 1, chunk = (int)blockIdx.x & 1;
  const int p0 = ptile * 64;
  const int sb = chunk ? 33 : 0, ns = chunk ? 32 : 33;
  _Float16* K3c = chunk ? K3b : K3a;

  const int p4 = t & 15, dp = 2 * (t >> 4);  // thread stages rows (dp, dp+1), p = 4*p4..
  const int wbase = 256 * p4 + 16 * ((dp >> 3) ^ (p4 & 3)) + 2 * (dp & 7);
  const int l15 = lane & 15;
  const int su = 16 * ((lane >> 4) ^ (l15 >> 2));  // read swizzle (nf-independent)

  const float* gT = T + (size_t)(sb * 32 + dp) * PTOT + p0 + 4 * p4;

#define LOADW(Q0, Q1, S)                                      \
  {                                                           \
    const float* gp = gT + (size_t)(S) * (32 * PTOT);         \
    Q0 = *(const float4*)gp;                                  \
    Q1 = *(const float4*)(gp + PTOT);                         \
  }
#define WRITEW(BUF, Q0, Q1)                                   \
  {                                                           \
    char* wb = (char*)(BUF) + wbase;                          \
    *(unsigned int*)(wb + 0)   = pk16(Q0.x, Q1.x);            \
    *(unsigned int*)(wb + 64)  = pk16(Q0.y, Q1.y);            \
    *(unsigned int*)(wb + 128) = pk16(Q0.z, Q1.z);            \
    *(unsigned int*)(wb + 192) = pk16(Q0.w, Q1.w);            \
  }
#define COMPUTEW(BUF, SG)                                                         \
  {                                                                               \
    const _Float16* wfp = Wf + (size_t)(SG) * 4096 + w * 1024 + (size_t)lane * 8; \
    const h8 a0 = *(const h8*)wfp;                                                \
    const h8 a1 = *(const h8*)(wfp + 512);                                        \
    _Pragma("unroll") for (int nf = 0; nf < 4; ++nf) {                            \
      const h8 b = *(const h8*)((const char*)(BUF) + 64 * (nf * 16 + l15) + su);  \
      acc0[nf] = __builtin_amdgcn_mfma_f32_16x16x32_f16(a0, b, acc0[nf], 0, 0, 0); \
      acc1[nf] = __builtin_amdgcn_mfma_f32_16x16x32_f16(a1, b, acc1[nf], 0, 0, 0); \
    }                                                                             \
  }

  f32x4 acc0[4] = {}, acc1[4] = {};
  float4 A0, A1, Br0, Br1;
  LOADW(A0, A1, 0)
  LOADW(Br0, Br1, 1)
  WRITEW(Tb0, A0, A1)
  __syncthreads();
  for (int s = 0; s < ns; s += 2) {
    if (s + 2 < ns) LOADW(A0, A1, s + 2)
    if (s + 1 < ns) WRITEW(Tb1, Br0, Br1)
    COMPUTEW(Tb0, sb + s)
    __syncthreads();
    if (s + 1 < ns) {
      if (s + 3 < ns) LOADW(Br0, Br1, s + 3)
      if (s + 2 < ns) WRITEW(Tb0, A0, A1)
      COMPUTEW(Tb1, sb + s + 1)
      __syncthreads();
    }
  }
  const int rb = (lane >> 4) << 2;
#pragma unroll
  for (int nf = 0; nf < 4; ++nf)
#pragma unroll
    for (int r = 0; r < 4; ++r) {
      K3c[(size_t)(w * 32 + rb + r) * PTOT + p0 + nf * 16 + l15] = (_Float16)acc0[nf][r];
      K3c[(size_t)(w * 32 + 16 + rb + r) * PTOT + p0 + nf * 16 + l15] = (_Float16)acc1[nf][r];
    }
#undef LOADW
#undef WRITEW
#undef COMPUTEW
}

// ---- k_sum: K3h = K3a + K3b (f16, 2M elems)
__global__ __launch_bounds__(256) void k_sum(const _Float16* __restrict__ A,
                                             const _Float16* __restrict__ B,
                                             _Float16* __restrict__ O) {
  const size_t i = ((size_t)blockIdx.x * 256 + threadIdx.x) * 8;
  const h8 a = *(const h8*)(A + i);
  const h8 b = *(const h8*)(B + i);
  *(h8*)(O + i) = a + b;
}

// ---- k_qf: grid 512 = 128 z-tiles x 4 i-classes; block 256 = 4 waves (2 zg x 2 kg).
// Wave tile 64z x 64k (m=2, n=2, kc=8). B tile [128k][128j] f16 dbuf in LDS.
__global__ __launch_bounds__(256, 2) void k_qf(const float* __restrict__ features,
                                               const _Float16* __restrict__ K3,
                                               float* __restrict__ out) {
  __shared__ __align__(16) _Float16 B0[16384];
  __shared__ __align__(16) _Float16 B1[16384];
  __shared__ _Float16 fT[32 * 136];
  const int t = threadIdx.x, lane = t & 63, w = t >> 6;
  const int zg = w >> 1, kg = w & 1, hg = lane >> 5, l31 = lane & 31;
  const int zb = blockIdx.x >> 2, ic = blockIdx.x & 3;
  const int z0 = zb * 128, i0 = ic * 32;

  // f-tile [z 0..127][j 0..127] f16, XOR-swizzled, into B0 (transient)
  {
    const int row = t >> 1, hf = t & 1;
    const float* fr = features + (size_t)(z0 + row) * NIN;
    const int rs = (row & 7) << 4;
#pragma unroll
    for (int qb = 0; qb < 8; ++qb) {
      h8 v;
#pragma unroll
      for (int e = 0; e < 8; ++e) {
        const int j = hf * 64 + qb * 8 + e;
        v[e] = (j == 0) ? (_Float16)1.0f : (_Float16)fr[j - 1];
      }
      *(h8*)((char*)B0 + row * 256 + (((hf * 8 + qb) * 16) ^ rs)) = v;
    }
  }
  // fT[i 0..31][z 0..127] (fi lookup table, transposed for conflict-free reads)
  {
    const int z = t >> 1, ih = t & 1;
#pragma unroll
    for (int q = 0; q < 16; ++q) {
      const int il = ih * 16 + q, gi = i0 + il;
      const float fv = (gi == 0) ? 1.0f : features[(size_t)(z0 + z) * NIN + gi - 1];
      fT[il * 136 + z] = (_Float16)fv;
    }
  }
  __syncthreads();

  // fj regs: per lane, rows (zg*64 + m*32 + l31), j = kc*16 + hg*8 + e
  h8 fj8[2][8];
#pragma unroll
  for (int m = 0; m < 2; ++m) {
    const int rowm = zg * 64 + m * 32 + l31;
    const int rs = (rowm & 7) << 4;
#pragma unroll
    for (int kc = 0; kc < 8; ++kc)
      fj8[m][kc] = *(const h8*)((const char*)B0 + rowm * 256 + (((kc * 2 + hg) * 16) ^ rs));
  }
  __syncthreads();

  // B staging: linear LDS dest, inverse-swizzled global source (rule #21)
  const _Float16* Kbase = K3 + (size_t)i0 * 128;
#define STAGE_B(BUF, IPH)                                                      \
  {                                                                            \
    const _Float16* src = Kbase + (IPH) * 128;                                 \
    _Pragma("unroll") for (int r = 0; r < 8; ++r) {                            \
      const int Lb = r * 4096 + w * 1024;                                      \
      const int row = (Lb >> 8) + (lane >> 4);                                 \
      const int us = (lane & 15) ^ (row & 7);                                  \
      gl16(src + (size_t)row * PTOT + us * 8, (char*)(BUF) + Lb);              \
    }                                                                          \
  }

  f32x16 acc[2][2] = {};
  STAGE_B(B0, 0)
  __syncthreads();

  const int rs0 = (l31 & 7) << 4;  // swizzle term: rows kg*64(+32)+l31 -> l31&7
  const int brow0 = (kg * 64 + l31) * 256;
  const int brow1 = (kg * 64 + 32 + l31) * 256;

#define PHASE(CURB, NXTB, PH, DO_STAGE)                                        \
  {                                                                            \
    if (DO_STAGE) STAGE_B(NXTB, (PH) + 1)                                      \
    const _Float16 f0 = fT[(PH) * 136 + zg * 64 + l31];                        \
    const _Float16 f1 = fT[(PH) * 136 + zg * 64 + 32 + l31];                   \
    const h2 fi0 = {f0, f0};                                                   \
    const h2 fi1 = {f1, f1};                                                   \
    _Pragma("unroll") for (int kc = 0; kc < 8; ++kc) {                         \
      const int uoff = ((kc * 2 + hg) * 16) ^ rs0;                             \
      const h8 b0 = *(const h8*)((const char*)(CURB) + brow0 + uoff);          \
      const h8 b1 = *(const h8*)((const char*)(CURB) + brow1 + uoff);          \
      h8 a0, a1;                                                               \
      _Pragma("unroll") for (int r = 0; r < 4; ++r) {                          \
        const h2 j0 = {fj8[0][kc][2 * r], fj8[0][kc][2 * r + 1]};              \
        const h2 j1 = {fj8[1][kc][2 * r], fj8[1][kc][2 * r + 1]};              \
        const h2 p0 = fi0 * j0;                                                \
        const h2 p1 = fi1 * j1;                                                \
        a0[2 * r] = p0[0]; a0[2 * r + 1] = p0[1];                              \
        a1[2 * r] = p1[0]; a1[2 * r + 1] = p1[1];                              \
      }                                                                        \
      acc[0][0] = __builtin_amdgcn_mfma_f32_32x32x16_f16(a0, b0, acc[0][0], 0, 0, 0); \
      acc[0][1] = __builtin_amdgcn_mfma_f32_32x32x16_f16(a0, b1, acc[0][1], 0, 0, 0); \
      acc[1][0] = __builtin_amdgcn_mfma_f32_32x32x16_f16(a1, b0, acc[1][0], 0, 0, 0); \
      acc[1][1] = __builtin_amdgcn_mfma_f32_32x32x16_f16(a1, b1, acc[1][1], 0, 0, 0); \
    }                                                                          \
    __syncthreads();                                                           \
  }

  for (int pb = 0; pb < 16; ++pb) {
    PHASE(B0, B1, pb * 2, true)
    PHASE(B1, B0, pb * 2 + 1, (pb < 15))
  }

  // C/D 32x32: col = l31, row = (r&3) + 8*(r>>2) + 4*hg
  const int kq = kg * 64 + l31;
#pragma unroll
  for (int m = 0; m < 2; ++m)
#pragma unroll
    for (int n = 0; n < 2; ++n)
#pragma unroll
      for (int r = 0; r < 16; ++r) {
        const int zr = (r & 3) + ((r >> 2) << 3) + (hg << 2);
        const int z = z0 + zg * 64 + m * 32 + zr;
        atomicAdd(out + (size_t)z * KOUT + kq + n * 32, acc[m][n][r]);
      }
}

extern "C" void kernel_launch(void* const* d_in, const int* in_sizes, int n_in,
                              void* d_out, int out_size, void* d_ws, size_t ws_size,
                              hipStream_t stream) {
  const float* features = (const float*)d_in[0];  // [16384, 127]
  const float* W        = (const float*)d_in[1];  // [128, 2080]
  const float* T        = (const float*)d_in[2];  // [2080, 16384]
  float* out = (float*)d_out;                     // [16384, 128] f32

  _Float16* K3h = (_Float16*)d_ws;                // [128, 16384] f16 (4 MB)
  _Float16* Wf  = K3h + (size_t)2 * 1024 * 1024;  // 532 KB, ws total ~4.6 MB
  _Float16* K3a = (_Float16*)d_out;               // partials in d_out scratch (8 MB)
  _Float16* K3b = K3a + (size_t)2 * 1024 * 1024;

  k_wf<<<dim3(130), dim3(256), 0, stream>>>(W, Wf);
  k_wt<<<dim3(512), dim3(256), 0, stream>>>(T, Wf, K3a, K3b);
  k_sum<<<dim3(1024), dim3(256), 0, stream>>>(K3a, K3b, K3h);
  (void)hipMemsetAsync(d_out, 0, (size_t)ZTOT * KOUT * sizeof(float), stream);
  k_qf<<<dim3(512), dim3(256), 0, stream>>>(features, K3h, out);
}